// Round 13
// baseline (3945.900 us; speedup 1.0000x reference)
//
#include <hip/hip_runtime.h>
#include <math.h>

#define NB 256
#define NS 128
#define NCOL 64
#define NT 60
#define DENC 512
#define DRNN 512
#define DATT 512
#define DACT 128
#define DTYP 64
#define DG 2048
#define NEGV (-1e9f)
#define NBH 131072      // NB*DRNN
#define NROW 15360      // NT*NB
#define RPW 512         // ptrq_all row width
#define NRP 2688        // r1(2048)|ptr(512)|w_mem(1)|pad : 21 tiles of 128

typedef unsigned short ushort_t;
typedef __attribute__((ext_vector_type(8))) short short8;
typedef __attribute__((ext_vector_type(4))) float f32x4;

__device__ __forceinline__ float sigf(float x) { return 1.0f / (1.0f + __expf(-x)); }
__device__ __forceinline__ float tanhfast(float x) {
  x = fminf(fmaxf(x, -15.0f), 15.0f);
  float e = __expf(-2.0f * x);
  return (1.0f - e) / (1.0f + e);
}
__device__ __forceinline__ ushort_t f2bf(float f) {
  union { float f; unsigned u; } v; v.f = f;
  unsigned r = v.u + 0x7fffu + ((v.u >> 16) & 1u);
  return (ushort_t)(r >> 16);
}
__device__ __forceinline__ float bf2f(ushort_t b) {
  union { unsigned u; float f; } v; v.u = ((unsigned)b) << 16; return v.f;
}
__device__ __forceinline__ short8 cvt8(const float* p) {
  f32x4 x = *(const f32x4*)p, y = *(const f32x4*)(p + 4);
  short8 r;
  r[0]=(short)f2bf(x[0]); r[1]=(short)f2bf(x[1]); r[2]=(short)f2bf(x[2]); r[3]=(short)f2bf(x[3]);
  r[4]=(short)f2bf(y[0]); r[5]=(short)f2bf(y[1]); r[6]=(short)f2bf(y[2]); r[7]=(short)f2bf(y[3]);
  return r;
}

// -------------------------------------------------------------------------
__global__ __launch_bounds__(256) void zero_kernel(float* __restrict__ p, int n) {
  int i = blockIdx.x * 256 + threadIdx.x;
  if (i < n) p[i] = 0.0f;
}

__global__ __launch_bounds__(256) void cvt_bf16_kernel(const float* __restrict__ src,
    ushort_t* __restrict__ dst, int n8)
{
  int i = blockIdx.x * 256 + threadIdx.x;
  if (i < n8) *(short8*)&dst[(size_t)i * 8] = cvt8(src + (size_t)i * 8);
}

// ---------------- mega weight-pack: all 8 packs in one launch --------------
#define S0 2752512   // W_ih  -> WpG
#define S1 1048576   // W_hh  -> WpG (K0=1344)
#define S2 262144    // W_att_q (transposed) -> WqTp
#define S3 524288    // W_att_vec -> WpV
#define S4 1048576   // W_r1 -> WpRP
#define S5 262144    // W_ptr -> WpRP (N0=2048)
#define S6 512       // w_mem -> WpRP (N0=2560)
#define S7 65536     // W_col_in -> WpCI
#define PACK_TOT (S0+S1+S2+S3+S4+S5+S6+S7)

__global__ __launch_bounds__(256) void pack_all(
    const float* __restrict__ W_ih, const float* __restrict__ W_hh,
    const float* __restrict__ W_att_q, const float* __restrict__ W_att_vec,
    const float* __restrict__ W_r1, const float* __restrict__ W_ptr,
    const float* __restrict__ w_mem, const float* __restrict__ W_col_in,
    ushort_t* __restrict__ WpG, ushort_t* __restrict__ WqTp,
    ushort_t* __restrict__ WpV, ushort_t* __restrict__ WpRP,
    ushort_t* __restrict__ WpCI)
{
  long idx = (long)blockIdx.x * 256 + threadIdx.x;
  if (idx < S0) {
    int k = (int)(idx >> 11), n = (int)(idx & 2047);
    WpG[((size_t)(k >> 3) * DG + n) * 8 + (k & 7)] = f2bf(W_ih[(size_t)k * DG + n]);
    return;
  }
  idx -= S0;
  if (idx < S1) {
    int k = (int)(idx >> 11), n = (int)(idx & 2047);
    int gk = k + 1344;
    WpG[((size_t)(gk >> 3) * DG + n) * 8 + (gk & 7)] = f2bf(W_hh[(size_t)k * DG + n]);
    return;
  }
  idx -= S1;
  if (idx < S2) {
    int r = (int)(idx >> 9), d = (int)(idx & 511);
    WqTp[((size_t)(d >> 3) * 512 + r) * 8 + (d & 7)] = f2bf(W_att_q[(size_t)r * 512 + d]);
    return;
  }
  idx -= S2;
  if (idx < S3) {
    int k = (int)(idx >> 9), n = (int)(idx & 511);
    WpV[((size_t)(k >> 3) * 512 + n) * 8 + (k & 7)] = f2bf(W_att_vec[(size_t)k * 512 + n]);
    return;
  }
  idx -= S3;
  if (idx < S4) {
    int k = (int)(idx >> 11), n = (int)(idx & 2047);
    WpRP[((size_t)(k >> 3) * NRP + n) * 8 + (k & 7)] = f2bf(W_r1[(size_t)k * DG + n]);
    return;
  }
  idx -= S4;
  if (idx < S5) {
    int k = (int)(idx >> 9), n = (int)(idx & 511);
    WpRP[((size_t)(k >> 3) * NRP + 2048 + n) * 8 + (k & 7)] = f2bf(W_ptr[(size_t)k * 512 + n]);
    return;
  }
  idx -= S5;
  if (idx < S6) {
    int k = (int)idx;
    WpRP[((size_t)(k >> 3) * NRP + 2560) * 8 + (k & 7)] = f2bf(w_mem[k]);
    return;
  }
  idx -= S6;
  if (idx < S7) {
    int k = (int)(idx >> 7), n = (int)(idx & 127);
    WpCI[((size_t)(k >> 3) * 128 + n) * 8 + (k & 7)] = f2bf(W_col_in[(size_t)k * 128 + n]);
  }
}

// Wr2p packed [(2048/8)][128][8]
__global__ __launch_bounds__(256) void r2p_kernel(const float* __restrict__ W_r2,
    const float* __restrict__ prod_embed, const float* __restrict__ b_r2,
    const float* __restrict__ b_lin, ushort_t* __restrict__ Wr2p,
    float* __restrict__ bias2)
{
  int idx = blockIdx.x * 256 + threadIdx.x;
  if (idx >= 2049 * 98) return;
  int k = idx / 98, j = idx - k * 98;
  const float* pe = prod_embed + (size_t)j * DACT;
  if (k < 2048) {
    const float* wr = W_r2 + (size_t)k * DACT;
    float a = 0.f;
    #pragma unroll 8
    for (int d = 0; d < DACT; ++d) a = fmaf(wr[d], pe[d], a);
    Wr2p[((size_t)(k >> 3) * 128 + j) * 8 + (k & 7)] = f2bf(a);
  } else {
    float a = b_lin[j];
    #pragma unroll 8
    for (int d = 0; d < DACT; ++d) a = fmaf(b_r2[d], pe[d], a);
    bias2[j] = a;
  }
}

// appear_all[t][b][c]
__global__ __launch_bounds__(64) void appear_kernel(const int* __restrict__ action_kind,
    const int* __restrict__ tgt_lens, const int* __restrict__ col_ids,
    float* __restrict__ appear_all)
{
  int b = blockIdx.x, c = threadIdx.x;
  float ap = 0.f;
  int tl = tgt_lens[b];
  for (int t = 0; t < NT; ++t) {
    appear_all[((size_t)t * NB + b) * 64 + c] = ap;
    if (t < tl && action_kind[b * NT + t] == 2 && col_ids[b * NT + t] == c) ap = 1.f;
  }
}

// standalone MFMA GEMM, A f32 (used for colin only)
__global__ __launch_bounds__(256) void gemm_bf16(
    const float* __restrict__ A1, int lda1,
    const ushort_t* __restrict__ Bp, ushort_t* __restrict__ Cb, int ldc,
    int N, int K)
{
  __shared__ short As[2][4096];
  __shared__ short Bs[2][4096];
  const int tid = threadIdx.x;
  const int lane = tid & 63, w = tid >> 6;
  const int wr = w >> 1, wc = w & 1;
  const int mBase = blockIdx.y * 64, nBase = blockIdx.x * 64;
  const int nt = K >> 6;
  f32x4 ra0[2], ra1[2];
  short8 rb[2];
  auto issue = [&](int kt) {
    #pragma unroll
    for (int s = 0; s < 2; ++s) {
      int slot = tid + s * 256;
      int kc = slot >> 6, m = slot & 63;
      int k0 = (kt << 6) + kc * 8;
      const float* p = A1 + (size_t)(mBase + m) * lda1 + k0;
      ra0[s] = *(const f32x4*)p;
      ra1[s] = *(const f32x4*)(p + 4);
      rb[s] = *(const short8*)(Bp + ((size_t)(k0 >> 3) * N + nBase + m) * 8);
    }
  };
  auto store = [&](int buf) {
    #pragma unroll
    for (int s = 0; s < 2; ++s) {
      int slot = tid + s * 256;
      short8 av;
      av[0]=(short)f2bf(ra0[s][0]); av[1]=(short)f2bf(ra0[s][1]);
      av[2]=(short)f2bf(ra0[s][2]); av[3]=(short)f2bf(ra0[s][3]);
      av[4]=(short)f2bf(ra1[s][0]); av[5]=(short)f2bf(ra1[s][1]);
      av[6]=(short)f2bf(ra1[s][2]); av[7]=(short)f2bf(ra1[s][3]);
      *(short8*)&As[buf][slot * 8] = av;
      *(short8*)&Bs[buf][slot * 8] = rb[s];
    }
  };
  f32x4 z4 = {0.f,0.f,0.f,0.f};
  f32x4 acc[2][2] = {{z4,z4},{z4,z4}};
  issue(0); store(0);
  __syncthreads();
  int cur = 0;
  for (int kt = 0; kt < nt; ++kt) {
    bool more = (kt + 1 < nt);
    if (more) issue(kt + 1);
    #pragma unroll
    for (int kk = 0; kk < 2; ++kk) {
      int ko = kk * 4 + (lane >> 4);
      short8 af[2], bfr[2];
      #pragma unroll
      for (int f = 0; f < 2; ++f) {
        int row = wr * 32 + f * 16 + (lane & 15);
        af[f] = *(const short8*)&As[cur][(ko * 64 + row) * 8];
        int col = wc * 32 + f * 16 + (lane & 15);
        bfr[f] = *(const short8*)&Bs[cur][(ko * 64 + col) * 8];
      }
      #pragma unroll
      for (int i = 0; i < 2; ++i)
        #pragma unroll
        for (int j = 0; j < 2; ++j)
          acc[i][j] = __builtin_amdgcn_mfma_f32_16x16x32_bf16(af[i], bfr[j], acc[i][j], 0, 0, 0);
    }
    if (more) store(cur ^ 1);
    __syncthreads();
    cur ^= 1;
  }
  #pragma unroll
  for (int i = 0; i < 2; ++i)
    #pragma unroll
    for (int j = 0; j < 2; ++j)
      #pragma unroll
      for (int r = 0; r < 4; ++r) {
        int row = mBase + wr * 32 + i * 16 + (lane >> 4) * 4 + r;
        int col = nBase + wc * 32 + j * 16 + (lane & 15);
        Cb[(size_t)row * ldc + col] = f2bf(acc[i][j][r]);
      }
}

// ---------------- encWq: A-in-LDS, n-loop, B-prefetch; also emits enc_b ----
__global__ __launch_bounds__(256) void gemm_encwq(
    const float* __restrict__ enc, const ushort_t* __restrict__ WqTp,
    ushort_t* __restrict__ encWq, ushort_t* __restrict__ enc_b)
{
  __shared__ short Asm[32768];
  const int tid = threadIdx.x;
  const int lane = tid & 63, w = tid >> 6;
  const int wr = w >> 1, wc = w & 1;
  const int mBase = blockIdx.x * 64;
  #pragma unroll
  for (int it = 0; it < 16; ++it) {
    int o = tid + it * 256;
    int row = o >> 6, c = o & 63;
    short8 v = cvt8(enc + (size_t)(mBase + row) * 512 + c * 8);
    *(short8*)&Asm[row * 512 + ((c ^ (row & 7)) * 8)] = v;
    *(short8*)(enc_b + (size_t)(mBase + row) * 512 + c * 8) = v;
  }
  __syncthreads();
  for (int nt = 0; nt < 8; ++nt) {
    f32x4 z4 = {0.f,0.f,0.f,0.f};
    f32x4 acc[2][2] = {{z4,z4},{z4,z4}};
    short8 bb[2][4];
    auto loadBf = [&](int kt, short8* dst) {
      #pragma unroll
      for (int kk = 0; kk < 2; ++kk)
        #pragma unroll
        for (int f = 0; f < 2; ++f) {
          int ko = kt * 8 + kk * 4 + (lane >> 4);
          int col = nt * 64 + wc * 32 + f * 16 + (lane & 15);
          dst[kk * 2 + f] = *(const short8*)(WqTp + ((size_t)ko * 512 + col) * 8);
        }
    };
    loadBf(0, bb[0]);
    loadBf(1, bb[1]);
    #pragma unroll
    for (int kt = 0; kt < 8; ++kt) {
      short8 cur[4];
      #pragma unroll
      for (int i = 0; i < 4; ++i) cur[i] = bb[kt & 1][i];
      if (kt + 2 < 8) loadBf(kt + 2, bb[kt & 1]);
      #pragma unroll
      for (int kk = 0; kk < 2; ++kk) {
        int ko = kt * 8 + kk * 4 + (lane >> 4);
        short8 af[2];
        #pragma unroll
        for (int f = 0; f < 2; ++f) {
          int row = wr * 32 + f * 16 + (lane & 15);
          af[f] = *(const short8*)&Asm[row * 512 + ((ko ^ (row & 7)) * 8)];
        }
        #pragma unroll
        for (int i = 0; i < 2; ++i)
          #pragma unroll
          for (int j = 0; j < 2; ++j)
            acc[i][j] = __builtin_amdgcn_mfma_f32_16x16x32_bf16(af[i], cur[kk * 2 + j], acc[i][j], 0, 0, 0);
      }
    }
    #pragma unroll
    for (int i = 0; i < 2; ++i)
      #pragma unroll
      for (int j = 0; j < 2; ++j)
        #pragma unroll
        for (int r = 0; r < 4; ++r) {
          int row = mBase + wr * 32 + i * 16 + (lane >> 4) * 4 + r;
          int col = nt * 64 + wc * 32 + j * 16 + (lane & 15);
          encWq[(size_t)row * 512 + col] = f2bf(acc[i][j][r]);
        }
  }
}

// ---------------- core 64x64 MFMA tile engine ------------------------------
template <class FA, class FB, class FE>
__device__ __forceinline__ void gemm_core(char* smem, FA loadA, FB loadB,
    int ktBeg, int ktEnd, FE epi)
{
  short* As = (short*)smem;
  short* Bs = (short*)smem + 8192;
  const int tid = threadIdx.x;
  const int lane = tid & 63, w = tid >> 6;
  const int wr = w >> 1, wc = w & 1;
  f32x4 z4 = {0.f,0.f,0.f,0.f};
  f32x4 acc[2][2] = {{z4,z4},{z4,z4}};
  short8 pa[2], pb[2];
  auto issue = [&](int kt) {
    #pragma unroll
    for (int s = 0; s < 2; ++s) {
      int slot = tid + s * 256;
      int kc = slot >> 6;
      int k = (kt << 6) + (kc << 3);
      pa[s] = loadA(k);
      pb[s] = loadB(slot & 63, k);
    }
  };
  auto store = [&](int buf) {
    #pragma unroll
    for (int s = 0; s < 2; ++s) {
      int slot = tid + s * 256;
      *(short8*)&As[buf * 4096 + slot * 8] = pa[s];
      *(short8*)&Bs[buf * 4096 + slot * 8] = pb[s];
    }
  };
  issue(ktBeg); store(0);
  __syncthreads();
  int cur = 0;
  for (int kt = ktBeg; kt < ktEnd; ++kt) {
    bool more = (kt + 1 < ktEnd);
    if (more) issue(kt + 1);
    #pragma unroll
    for (int kk = 0; kk < 2; ++kk) {
      int ko = kk * 4 + (lane >> 4);
      short8 af[2], bfr[2];
      #pragma unroll
      for (int f = 0; f < 2; ++f) {
        int row = wr * 32 + f * 16 + (lane & 15);
        af[f] = *(const short8*)&As[cur * 4096 + (ko * 64 + row) * 8];
        int col = wc * 32 + f * 16 + (lane & 15);
        bfr[f] = *(const short8*)&Bs[cur * 4096 + (ko * 64 + col) * 8];
      }
      #pragma unroll
      for (int i = 0; i < 2; ++i)
        #pragma unroll
        for (int j = 0; j < 2; ++j)
          acc[i][j] = __builtin_amdgcn_mfma_f32_16x16x32_bf16(af[i], bfr[j], acc[i][j], 0, 0, 0);
    }
    if (more) store(cur ^ 1);
    __syncthreads();
    cur ^= 1;
  }
  #pragma unroll
  for (int i = 0; i < 2; ++i)
    #pragma unroll
    for (int j = 0; j < 2; ++j)
      #pragma unroll
      for (int r = 0; r < 4; ++r) {
        int rl = wr * 32 + i * 16 + (lane >> 4) * 4 + r;
        int cl = wc * 32 + j * 16 + (lane & 15);
        epi(rl, cl, acc[i][j][r]);
      }
}

// ---------------- K1: gates GEMM, split-K x4, f32 out, XCD-swizzled --------
__global__ __launch_bounds__(256) void k1_gates(
    const int* __restrict__ action_kind, const int* __restrict__ tgt_lens,
    const int* __restrict__ prod_ids, const int* __restrict__ col_ids,
    const int* __restrict__ parent_prod, const int* __restrict__ parent_type,
    const int* __restrict__ parent_time,
    const float* __restrict__ prod_embed, const float* __restrict__ type_embed,
    const ushort_t* __restrict__ WpG, const ushort_t* __restrict__ colin_b,
    const ushort_t* __restrict__ att_all, const ushort_t* __restrict__ hist_u,
    float* __restrict__ gates0, float* __restrict__ gates1,
    float* __restrict__ gates2, float* __restrict__ gates3, int t)
{
  __shared__ __align__(16) char smem[32768];
  const int tid = threadIdx.x;
  const int bid = blockIdx.x;
  const int x = bid & 7, j = bid >> 3;
  const int mb = x >> 1;
  const int ks = j >> 4;
  const int nb = ((x & 1) << 4) | (j & 15);
  const int mBase = mb * 64, nBase = nb * 64;
  const int b = mBase + (tid & 63);
  int kp = action_kind[b * NT + t - 1];
  int pp = prod_ids[b * NT + t - 1];
  int cp = col_ids[b * NT + t - 1];
  bool pv = (t - 1) < tgt_lens[b];
  int fp = parent_prod[b * NT + t];
  int ft = parent_type[b * NT + t];
  int ptm = parent_time[b * NT + t];
  const ushort_t* hist_prev = hist_u + (size_t)(t - 1) * NBH;
  const ushort_t* att_prev = att_all + (size_t)(t - 1) * NB * DATT;
  auto loadA = [&](int k) -> short8 {
    short8 z = {0,0,0,0,0,0,0,0};
    if (k < 128) {
      if (!pv) return z;
      if (kp == 2) return *(const short8*)(colin_b + ((size_t)(b * NCOL + cp) * DACT + k));
      int row = (kp == 1) ? 97 : pp;
      return cvt8(prod_embed + (size_t)row * DACT + k);
    } else if (k < 640) {
      return *(const short8*)(att_prev + (size_t)b * DATT + (k - 128));
    } else if (k < 768) {
      return cvt8(prod_embed + (size_t)fp * DACT + (k - 640));
    } else if (k < 832) {
      return cvt8(type_embed + (size_t)ft * DTYP + (k - 768));
    } else if (k < 1344) {
      return *(const short8*)(hist_u + (size_t)ptm * NBH + (size_t)b * DRNN + (k - 832));
    } else {
      return *(const short8*)(hist_prev + (size_t)b * DRNN + (k - 1344));
    }
  };
  auto loadB = [&](int n, int k) -> short8 {
    return *(const short8*)(WpG + ((size_t)(k >> 3) * DG + nBase + n) * 8);
  };
  float* gp = (ks == 0) ? gates0 : (ks == 1) ? gates1 : (ks == 2) ? gates2 : gates3;
  auto epi = [&](int rl, int cl, float v) {
    gp[(size_t)(mBase + rl) * DG + nBase + cl] = v;
  };
  const int kb0 = (ks == 0) ? 0 : (ks == 1) ? 8 : (ks == 2) ? 15 : 22;
  const int kb1 = (ks == 0) ? 8 : (ks == 1) ? 15 : (ks == 2) ? 22 : 29;
  gemm_core(smem, loadA, loadB, kb0, kb1, epi);
}

// ---------------- K234: LSTM+attention (blocks 0-255) ∥ attvec (256-287) ---
struct SmemK23 { float hq[DRNN]; float ml[4][2]; float cs[4][DENC]; };
__global__ __launch_bounds__(256) void k234(
    const float* __restrict__ g0, const float* __restrict__ g1,
    const float* __restrict__ g2, const float* __restrict__ g3,
    const float* __restrict__ b_lstm, float* __restrict__ cst,
    ushort_t* __restrict__ hist_t,
    const ushort_t* __restrict__ encWq, const ushort_t* __restrict__ enc_b,
    const int* __restrict__ enc_lens, ushort_t* __restrict__ ctxb,
    const ushort_t* __restrict__ WpV, ushort_t* __restrict__ att_t,
    unsigned* __restrict__ cnt, int t)
{
  __shared__ __align__(16) char smem[32768];
  const int bid = blockIdx.x, tid = threadIdx.x;
  if (bid < NB) {
    // ---- producer: LSTM + online-softmax attention for batch row b ----
    SmemK23* s = (SmemK23*)smem;
    int b = bid;
    const float* p0 = g0 + (size_t)b * DG;
    const float* p1 = g1 + (size_t)b * DG;
    const float* p2 = g2 + (size_t)b * DG;
    const float* p3 = g3 + (size_t)b * DG;
    #pragma unroll
    for (int r = 0; r < 2; ++r) {
      int j = tid + r * 256;
      float gi = p0[j] + p1[j] + p2[j] + p3[j] + b_lstm[j];
      float gf = p0[512+j] + p1[512+j] + p2[512+j] + p3[512+j] + b_lstm[512+j];
      float gg = p0[1024+j] + p1[1024+j] + p2[1024+j] + p3[1024+j] + b_lstm[1024+j];
      float go = p0[1536+j] + p1[1536+j] + p2[1536+j] + p3[1536+j] + b_lstm[1536+j];
      size_t ix = (size_t)b * DRNN + j;
      float cn = sigf(gf) * cst[ix] + sigf(gi) * tanhfast(gg);
      float hn = sigf(go) * tanhfast(cn);
      cst[ix] = cn;
      hist_t[ix] = f2bf(hn);
      s->hq[j] = hn;
    }
    __syncthreads();
    int w = tid >> 6, lane = tid & 63;
    int el = enc_lens[b];
    float q[8];
    #pragma unroll
    for (int j = 0; j < 8; ++j) q[j] = s->hq[lane * 8 + j];
    float m = -1e30f, lr = 0.f;
    float cacc[8];
    #pragma unroll
    for (int j = 0; j < 8; ++j) cacc[j] = 0.f;
    const ushort_t* eWb = encWq + (size_t)b * NS * DENC + lane * 8;
    const ushort_t* eb = enc_b + (size_t)b * NS * DENC + lane * 8;
    for (int sI = w; sI < el; sI += 4) {
      short8 xr = *(const short8*)(eWb + (size_t)sI * DENC);
      short8 er = *(const short8*)(eb + (size_t)sI * DENC);
      float d = 0.f;
      #pragma unroll
      for (int j = 0; j < 8; ++j) d = fmaf(bf2f((ushort_t)xr[j]), q[j], d);
      #pragma unroll
      for (int off = 32; off > 0; off >>= 1) d += __shfl_xor(d, off);
      float mn = fmaxf(m, d);
      float rr = __expf(m - mn), p = __expf(d - mn);
      lr = lr * rr + p;
      #pragma unroll
      for (int j = 0; j < 8; ++j) cacc[j] = cacc[j] * rr + p * bf2f((ushort_t)er[j]);
      m = mn;
    }
    if (lane == 0) { s->ml[w][0] = m; s->ml[w][1] = lr; }
    #pragma unroll
    for (int j = 0; j < 8; ++j) s->cs[w][lane * 8 + j] = cacc[j];
    __syncthreads();
    float M = fmaxf(fmaxf(s->ml[0][0], s->ml[1][0]), fmaxf(s->ml[2][0], s->ml[3][0]));
    float f0 = __expf(s->ml[0][0] - M), f1 = __expf(s->ml[1][0] - M);
    float f2 = __expf(s->ml[2][0] - M), f3 = __expf(s->ml[3][0] - M);
    float invL = 1.f / (f0 * s->ml[0][1] + f1 * s->ml[1][1] + f2 * s->ml[2][1] + f3 * s->ml[3][1]);
    #pragma unroll
    for (int rep = 0; rep < 2; ++rep) {
      int d = tid + rep * 256;
      ctxb[(size_t)b * DENC + d] =
          f2bf((f0 * s->cs[0][d] + f1 * s->cs[1][d] + f2 * s->cs[2][d] + f3 * s->cs[3][d]) * invL);
    }
    __syncthreads();
    if (tid == 0) {
      __threadfence();
      __hip_atomic_fetch_add(&cnt[b >> 6], 1u, __ATOMIC_RELEASE, __HIP_MEMORY_SCOPE_AGENT);
    }
  } else {
    // ---- consumer: attvec GEMM tile, waits for its 64 producer rows ----
    const int idx = bid - NB;
    const int mb = idx >> 3, nb = idx & 7;
    const int mBase = mb * 64, nBase = nb * 64;
    if (tid == 0) {
      unsigned target = 64u * (unsigned)(t + 1);
      while (__hip_atomic_load(&cnt[mb], __ATOMIC_RELAXED, __HIP_MEMORY_SCOPE_AGENT) < target)
        __builtin_amdgcn_s_sleep(8);
      (void)__hip_atomic_load(&cnt[mb], __ATOMIC_ACQUIRE, __HIP_MEMORY_SCOPE_AGENT);
    }
    __syncthreads();
    const int b = mBase + (tid & 63);
    auto loadA = [&](int k) -> short8 {
      if (k < 512) return *(const short8*)(ctxb + (size_t)b * DENC + k);
      return *(const short8*)(hist_t + (size_t)b * DRNN + (k - 512));
    };
    auto loadB = [&](int n, int k) -> short8 {
      return *(const short8*)(WpV + ((size_t)(k >> 3) * 512 + nBase + n) * 8);
    };
    auto epi = [&](int rl, int cl, float v) {
      att_t[(size_t)(mBase + rl) * DATT + nBase + cl] = f2bf(tanhfast(v));
    };
    gemm_core(smem, loadA, loadB, 0, 16, epi);
  }
}

// ---------------- tail: r1|ptr|gate GEMM, 64x128 tile, XCD-swizzled --------
__global__ __launch_bounds__(256) void kbig_r1ptr(const ushort_t* __restrict__ att_all,
    const ushort_t* __restrict__ WpRP, const float* __restrict__ b_r1,
    ushort_t* __restrict__ r1c, ushort_t* __restrict__ ptrq_all,
    float* __restrict__ gate_all, int rowBase)
{
  __shared__ short As[2][4096];
  __shared__ short Bs[2][8192];
  const int tid = threadIdx.x;
  const int lane = tid & 63, w = tid >> 6;
  const int wr = w >> 1, wc = w & 1;
  const int bid = blockIdx.x;
  const int x = bid & 7, j = bid >> 3;          // j in [0,315)
  const int mb = x * 15 + j / 21;
  const int ng = j % 21;
  const int mBase = mb * 64, nBase = ng * 128;
  short8 pa[2], pb[4];
  auto issue = [&](int kt) {
    #pragma unroll
    for (int s = 0; s < 2; ++s) {
      int slot = tid + s * 256;
      int kc = slot >> 6, m = slot & 63;
      int k = (kt << 6) + (kc << 3);
      pa[s] = *(const short8*)(att_all + ((size_t)rowBase + mBase + m) * DATT + k);
    }
    #pragma unroll
    for (int s = 0; s < 4; ++s) {
      int slot = tid + s * 256;
      int kc = slot >> 7, n = slot & 127;
      int k = (kt << 6) + (kc << 3);
      pb[s] = *(const short8*)(WpRP + ((size_t)(k >> 3) * NRP + nBase + n) * 8);
    }
  };
  auto store = [&](int buf) {
    #pragma unroll
    for (int s = 0; s < 2; ++s) {
      int slot = tid + s * 256;
      *(short8*)&As[buf][slot * 8] = pa[s];
    }
    #pragma unroll
    for (int s = 0; s < 4; ++s) {
      int slot = tid + s * 256;
      *(short8*)&Bs[buf][slot * 8] = pb[s];
    }
  };
  f32x4 z4 = {0.f,0.f,0.f,0.f};
  f32x4 acc[2][4] = {{z4,z4,z4,z4},{z4,z4,z4,z4}};
  issue(0); store(0);
  __syncthreads();
  int cur = 0;
  for (int kt = 0; kt < 8; ++kt) {
    bool more = (kt + 1 < 8);
    if (more) issue(kt + 1);
    #pragma unroll
    for (int kk = 0; kk < 2; ++kk) {
      int ko = kk * 4 + (lane >> 4);
      short8 af[2], bfr[4];
      #pragma unroll
      for (int f = 0; f < 2; ++f) {
        int row = wr * 32 + f * 16 + (lane & 15);
        af[f] = *(const short8*)&As[cur][(ko * 64 + row) * 8];
      }
      #pragma unroll
      for (int f = 0; f < 4; ++f) {
        int col = wc * 64 + f * 16 + (lane & 15);
        bfr[f] = *(const short8*)&Bs[cur][(ko * 128 + col) * 8];
      }
      #pragma unroll
      for (int i = 0; i < 2; ++i)
        #pragma unroll
        for (int jf = 0; jf < 4; ++jf)
          acc[i][jf] = __builtin_amdgcn_mfma_f32_16x16x32_bf16(af[i], bfr[jf], acc[i][jf], 0, 0, 0);
    }
    if (more) store(cur ^ 1);
    __syncthreads();
    cur ^= 1;
  }
  #pragma unroll
  for (int i = 0; i < 2; ++i)
    #pragma unroll
    for (int jf = 0; jf < 4; ++jf)
      #pragma unroll
      for (int r = 0; r < 4; ++r) {
        int rl = wr * 32 + i * 16 + (lane >> 4) * 4 + r;
        int col = nBase + wc * 64 + jf * 16 + (lane & 15);
        size_t gr = (size_t)rowBase + mBase + rl;
        float v = acc[i][jf][r];
        if (col < 2048)      r1c[(size_t)(mBase + rl) * DG + col] = f2bf(tanhfast(v + b_r1[col]));
        else if (col < 2560) ptrq_all[((size_t)(gr & 255) * NT + (gr >> 8)) * RPW + (col - 2048)] = f2bf(v);
        else if (col == 2560) gate_all[gr] = v;
      }
}

// ---------------- tail: logits GEMM (XCD-swizzled 1D grid, 240 blocks) -----
__global__ __launch_bounds__(256) void klogits(const ushort_t* __restrict__ r1c,
    const ushort_t* __restrict__ Wr2p, float* __restrict__ logits_all, int rowBase)
{
  __shared__ __align__(16) char smem[32768];
  const int tid = threadIdx.x;
  const int bid = blockIdx.x;
  const int x = bid & 7, j = bid >> 3;
  const int mb = x * 15 + (j >> 1);
  const int nb = j & 1;
  const int mBase = mb * 64, nBase = nb * 64;
  auto loadA = [&](int k) -> short8 {
    return *(const short8*)(r1c + (size_t)(mBase + (tid & 63)) * DG + k);
  };
  auto loadB = [&](int n, int k) -> short8 {
    return *(const short8*)(Wr2p + ((size_t)(k >> 3) * 128 + nBase + n) * 8);
  };
  auto epi = [&](int rl, int cl, float v) {
    logits_all[((size_t)rowBase + mBase + rl) * 128 + nBase + cl] = v;
  };
  gemm_core(smem, loadA, loadB, 0, 32, epi);
}

// ---------------- tail: w_c ------------------------------------------------
__global__ __launch_bounds__(256) void kwc(const ushort_t* __restrict__ ptrq_all,
    const ushort_t* __restrict__ colenc_b, float* __restrict__ w_c_all)
{
  __shared__ __align__(16) char smem[32768];
  const int tid = threadIdx.x;
  const int b = blockIdx.x;
  const int tt = tid & 63;
  auto loadA = [&](int k) -> short8 {
    short8 z = {0,0,0,0,0,0,0,0};
    if (tt >= NT) return z;
    return *(const short8*)(ptrq_all + ((size_t)b * NT + tt) * RPW + k);
  };
  auto loadB = [&](int n, int k) -> short8 {
    return *(const short8*)(colenc_b + ((size_t)b * NCOL + n) * 512 + k);
  };
  auto epi = [&](int rl, int cl, float v) {
    if (rl < NT) w_c_all[((size_t)rl * NB + b) * 64 + cl] = v;
  };
  gemm_core(smem, loadA, loadB, 0, 8, epi);
}

// ---------------- tail: per-(t,b) softmaxes + loss -------------------------
__global__ __launch_bounds__(64) void kfinal(
    const float* __restrict__ logits_all, const float* __restrict__ bias2,
    const float* __restrict__ w_c_all, const float* __restrict__ gate_all,
    const float* __restrict__ appear_all, const int* __restrict__ col_lens,
    const int* __restrict__ tgt_lens, const int* __restrict__ action_kind,
    const int* __restrict__ prod_ids, const int* __restrict__ col_ids,
    float* __restrict__ loss_tb)
{
  int row = blockIdx.x;
  int t = row >> 8, b = row & 255;
  int c = threadIdx.x;
  float l0 = logits_all[(size_t)row * 128 + c] + bias2[c];
  float l1 = (c + 64 < 98) ? logits_all[(size_t)row * 128 + 64 + c] + bias2[64 + c] : -1e30f;
  float m = fmaxf(l0, l1);
  #pragma unroll
  for (int off = 32; off > 0; off >>= 1) m = fmaxf(m, __shfl_down(m, off));
  m = __shfl(m, 0);
  float sv = __expf(l0 - m) + ((c + 64 < 98) ? __expf(l1 - m) : 0.f);
  #pragma unroll
  for (int off = 32; off > 0; off >>= 1) sv += __shfl_down(sv, off);
  sv = __shfl(sv, 0);
  float lseR = m + __logf(sv);
  int clen = col_lens[b];
  float gate = sigf(gate_all[row]);
  float ap = appear_all[(size_t)row * 64 + c];
  float wc = w_c_all[(size_t)row * 64 + c];
  float wv = wc * (ap * gate + (1.f - ap) * (1.f - gate));
  wv = (c < clen) ? wv : NEGV;
  float m2 = wv;
  #pragma unroll
  for (int off = 32; off > 0; off >>= 1) m2 = fmaxf(m2, __shfl_down(m2, off));
  m2 = __shfl(m2, 0);
  float s2 = __expf(wv - m2);
  #pragma unroll
  for (int off = 32; off > 0; off >>= 1) s2 += __shfl_down(s2, off);
  s2 = __shfl(s2, 0);
  float lse2 = m2 + __logf(s2);
  float csum = (c < clen) ? (wv - lse2) : 0.f;
  #pragma unroll
  for (int off = 32; off > 0; off >>= 1) csum += __shfl_down(csum, off);
  int kind = action_kind[b * NT + t];
  int cid = col_ids[b * NT + t];
  float wcid = __shfl(wv, cid);
  if (c == 0) {
    int pid = prod_ids[b * NT + t];
    bool valid = t < tgt_lens[b];
    int gj = (kind == 1) ? 97 : pid;
    float lgj = logits_all[(size_t)row * 128 + gj] + bias2[gj];
    float lp_rule = lgj - lseR;
    float lp_col = 0.8f * (wcid - lse2) + 0.2f * csum / (float)clen;
    float lp = (kind == 2) ? lp_col : lp_rule;
    loss_tb[row] = valid ? lp : 0.f;
  }
}

// -------------------------------------------------------------------------
__global__ __launch_bounds__(256) void loss_reduce(const float* __restrict__ loss_tb,
                                                   float* __restrict__ out) {
  int tid = threadIdx.x;
  float v = 0.f;
  for (int k = 0; k < NT; ++k) v += loss_tb[(size_t)k * NB + tid];
  #pragma unroll
  for (int off = 32; off > 0; off >>= 1) v += __shfl_down(v, off);
  __shared__ float part[4];
  if ((tid & 63) == 0) part[tid >> 6] = v;
  __syncthreads();
  if (tid == 0) out[0] = -(part[0] + part[1] + part[2] + part[3]) * (1.0f / NB);
}

// -------------------------------------------------------------------------
extern "C" void kernel_launch(void* const* d_in, const int* in_sizes, int n_in,
                              void* d_out, int out_size, void* d_ws, size_t ws_size,
                              hipStream_t stream) {
  const float* enc         = (const float*)d_in[0];
  const float* col_enc     = (const float*)d_in[1];
  const int*   enc_lens    = (const int*)d_in[2];
  const int*   col_lens    = (const int*)d_in[3];
  const int*   action_kind = (const int*)d_in[4];
  const int*   tgt_lens    = (const int*)d_in[5];
  const int*   prod_ids    = (const int*)d_in[6];
  const int*   col_ids     = (const int*)d_in[7];
  const int*   parent_prod = (const int*)d_in[8];
  const int*   parent_type = (const int*)d_in[9];
  const int*   parent_time = (const int*)d_in[10];
  const float* prod_embed  = (const float*)d_in[11];
  const float* type_embed  = (const float*)d_in[12];
  const float* b_lin       = (const float*)d_in[13];
  const float* W_ih        = (const float*)d_in[14];
  const float* W_hh        = (const float*)d_in[15];
  const float* b_lstm      = (const float*)d_in[16];
  const float* W_att_q     = (const float*)d_in[17];
  const float* W_att_vec   = (const float*)d_in[18];
  const float* W_r1        = (const float*)d_in[19];
  const float* b_r1        = (const float*)d_in[20];
  const float* W_r2        = (const float*)d_in[21];
  const float* b_r2        = (const float*)d_in[22];
  const float* W_col_in    = (const float*)d_in[23];
  const float* W_ptr       = (const float*)d_in[24];
  const float* w_mem       = (const float*)d_in[25];

  float* base = (float*)d_ws;
  size_t o = 0;
  float* cst    = base + o; o += 131072;
  unsigned* cnt = (unsigned*)(base + o); o += 64;
  float* gates0 = base + o; o += 524288;
  float* gates1 = base + o; o += 524288;
  float* gates2 = base + o; o += 524288;
  float* gates3 = base + o; o += 524288;
  int zeroN = (int)o;                                   // 2,228,288
  ushort_t* hist_u = (ushort_t*)(base + o); o += 3932160;   // loop; tail alias: logits_all
  float* logits_all = (float*)hist_u;
  ushort_t* colin_b = (ushort_t*)(base + o); o += 1048576;
  float* encWq_f    = base + o; o += 8388608;               // loop: encWq; tail alias: r1c
  ushort_t* encWq   = (ushort_t*)encWq_f;
  ushort_t* r1c     = (ushort_t*)encWq_f;
  float* encb_f     = base + o; o += 4194304;               // loop: enc_b; tail alias: colenc_b
  ushort_t* enc_b   = (ushort_t*)encb_f;
  ushort_t* colenc_b = (ushort_t*)encb_f;
  ushort_t* att_all  = (ushort_t*)(base + o); o += 3932160; // [15360][512] bf16
  ushort_t* ptrq_all = (ushort_t*)(base + o); o += 3932160; // [256][60][512] bf16; loop alias: ctxb
  ushort_t* ctxb     = ptrq_all;
  float* gate_all    = base + o; o += 15360;
  float* w_c_all     = base + o; o += 983040;
  float* appear_all  = base + o; o += 983040;
  float* loss_tb     = base + o; o += 15360;
  ushort_t* WpG   = (ushort_t*)(base + o); o += 1900544;
  ushort_t* WqTp  = (ushort_t*)(base + o); o += 131072;
  ushort_t* WpV   = (ushort_t*)(base + o); o += 262144;
  ushort_t* WpRP  = (ushort_t*)(base + o); o += 688128;     // [(512/8)][2688][8]
  ushort_t* WpCI  = (ushort_t*)(base + o); o += 32768;
  ushort_t* Wr2p  = (ushort_t*)(base + o); o += 131072;
  float* bias2    = base + o; o += 128;
  (void)ws_size; (void)in_sizes; (void)n_in; (void)out_size;

  zero_kernel<<<(zeroN + 255) / 256, 256, 0, stream>>>(base, zeroN);

  pack_all<<<(PACK_TOT + 255) / 256, 256, 0, stream>>>(
      W_ih, W_hh, W_att_q, W_att_vec, W_r1, W_ptr, w_mem, W_col_in,
      WpG, WqTp, WpV, WpRP, WpCI);
  r2p_kernel<<<(2049 * 98 + 255) / 256, 256, 0, stream>>>(W_r2, prod_embed, b_r2, b_lin, Wr2p, bias2);
  appear_kernel<<<NB, 64, 0, stream>>>(action_kind, tgt_lens, col_ids, appear_all);

  gemm_bf16<<<dim3(2, 256), 256, 0, stream>>>(col_enc, 512, WpCI, colin_b, 128, 128, 512);
  gemm_encwq<<<512, 256, 0, stream>>>(enc, WqTp, encWq, enc_b);

  // ---- recurrent loop: 2 nodes/step ----
  for (int t = 0; t < NT; ++t) {
    ushort_t* hist_t = hist_u + (size_t)t * NBH;
    if (t > 0)
      k1_gates<<<512, 256, 0, stream>>>(
          action_kind, tgt_lens, prod_ids, col_ids, parent_prod, parent_type,
          parent_time, prod_embed, type_embed, WpG, colin_b, att_all, hist_u,
          gates0, gates1, gates2, gates3, t);
    k234<<<NB + 32, 256, 0, stream>>>(gates0, gates1, gates2, gates3,
        b_lstm, cst, hist_t, encWq, enc_b, enc_lens, ctxb, WpV,
        att_all + (size_t)t * NB * DATT, cnt, t);
  }

  // ---- batched tail (2 chunks of 7680 rows) ----
  cvt_bf16_kernel<<<(1048576 + 255) / 256, 256, 0, stream>>>(col_enc, colenc_b, 1048576);
  for (int ch = 0; ch < 2; ++ch) {
    int rowBase = ch * 7680;
    kbig_r1ptr<<<2520, 256, 0, stream>>>(att_all, WpRP, b_r1, r1c,
                                         ptrq_all, gate_all, rowBase);
    klogits<<<240, 256, 0, stream>>>(r1c, Wr2p, logits_all, rowBase);
  }
  kwc<<<NB, 256, 0, stream>>>(ptrq_all, colenc_b, w_c_all);
  kfinal<<<NROW, 64, 0, stream>>>(logits_all, bias2, w_c_all, gate_all,
      appear_all, col_lens, tgt_lens, action_kind, prod_ids, col_ids, loss_tb);
  loss_reduce<<<1, 256, 0, stream>>>(loss_tb, (float*)d_out);
}

// Round 14
// 3048.855 us; speedup vs baseline: 1.2942x; 1.2942x over previous
//
#include <hip/hip_runtime.h>
#include <math.h>

#define NB 256
#define NS 128
#define NCOL 64
#define NT 60
#define DENC 512
#define DRNN 512
#define DATT 512
#define DACT 128
#define DTYP 64
#define DG 2048
#define NEGV (-1e9f)
#define NBH 131072      // NB*DRNN
#define NROW 15360      // NT*NB
#define RPW 512         // ptrq_all row width
#define NRP 2688        // r1(2048)|ptr(512)|w_mem(1)|pad : 21 tiles of 128

typedef unsigned short ushort_t;
typedef __attribute__((ext_vector_type(8))) short short8;
typedef __attribute__((ext_vector_type(4))) float f32x4;

__device__ __forceinline__ float sigf(float x) { return 1.0f / (1.0f + __expf(-x)); }
__device__ __forceinline__ float tanhfast(float x) {
  x = fminf(fmaxf(x, -15.0f), 15.0f);
  float e = __expf(-2.0f * x);
  return (1.0f - e) / (1.0f + e);
}
__device__ __forceinline__ ushort_t f2bf(float f) {
  union { float f; unsigned u; } v; v.f = f;
  unsigned r = v.u + 0x7fffu + ((v.u >> 16) & 1u);
  return (ushort_t)(r >> 16);
}
__device__ __forceinline__ float bf2f(ushort_t b) {
  union { unsigned u; float f; } v; v.u = ((unsigned)b) << 16; return v.f;
}
__device__ __forceinline__ short8 cvt8(const float* p) {
  f32x4 x = *(const f32x4*)p, y = *(const f32x4*)(p + 4);
  short8 r;
  r[0]=(short)f2bf(x[0]); r[1]=(short)f2bf(x[1]); r[2]=(short)f2bf(x[2]); r[3]=(short)f2bf(x[3]);
  r[4]=(short)f2bf(y[0]); r[5]=(short)f2bf(y[1]); r[6]=(short)f2bf(y[2]); r[7]=(short)f2bf(y[3]);
  return r;
}

// -------------------------------------------------------------------------
__global__ __launch_bounds__(256) void zero_kernel(float* __restrict__ p, int n) {
  int i = blockIdx.x * 256 + threadIdx.x;
  if (i < n) p[i] = 0.0f;
}

__global__ __launch_bounds__(256) void cvt_bf16_kernel(const float* __restrict__ src,
    ushort_t* __restrict__ dst, int n8)
{
  int i = blockIdx.x * 256 + threadIdx.x;
  if (i < n8) *(short8*)&dst[(size_t)i * 8] = cvt8(src + (size_t)i * 8);
}

// ---------------- mega weight-pack: all 8 packs in one launch --------------
#define S0 2752512
#define S1 1048576
#define S2 262144
#define S3 524288
#define S4 1048576
#define S5 262144
#define S6 512
#define S7 65536
#define PACK_TOT (S0+S1+S2+S3+S4+S5+S6+S7)

__global__ __launch_bounds__(256) void pack_all(
    const float* __restrict__ W_ih, const float* __restrict__ W_hh,
    const float* __restrict__ W_att_q, const float* __restrict__ W_att_vec,
    const float* __restrict__ W_r1, const float* __restrict__ W_ptr,
    const float* __restrict__ w_mem, const float* __restrict__ W_col_in,
    ushort_t* __restrict__ WpG, ushort_t* __restrict__ WqTp,
    ushort_t* __restrict__ WpV, ushort_t* __restrict__ WpRP,
    ushort_t* __restrict__ WpCI)
{
  long idx = (long)blockIdx.x * 256 + threadIdx.x;
  if (idx < S0) {
    int k = (int)(idx >> 11), n = (int)(idx & 2047);
    WpG[((size_t)(k >> 3) * DG + n) * 8 + (k & 7)] = f2bf(W_ih[(size_t)k * DG + n]);
    return;
  }
  idx -= S0;
  if (idx < S1) {
    int k = (int)(idx >> 11), n = (int)(idx & 2047);
    int gk = k + 1344;
    WpG[((size_t)(gk >> 3) * DG + n) * 8 + (gk & 7)] = f2bf(W_hh[(size_t)k * DG + n]);
    return;
  }
  idx -= S1;
  if (idx < S2) {
    int r = (int)(idx >> 9), d = (int)(idx & 511);
    WqTp[((size_t)(d >> 3) * 512 + r) * 8 + (d & 7)] = f2bf(W_att_q[(size_t)r * 512 + d]);
    return;
  }
  idx -= S2;
  if (idx < S3) {
    int k = (int)(idx >> 9), n = (int)(idx & 511);
    WpV[((size_t)(k >> 3) * 512 + n) * 8 + (k & 7)] = f2bf(W_att_vec[(size_t)k * 512 + n]);
    return;
  }
  idx -= S3;
  if (idx < S4) {
    int k = (int)(idx >> 11), n = (int)(idx & 2047);
    WpRP[((size_t)(k >> 3) * NRP + n) * 8 + (k & 7)] = f2bf(W_r1[(size_t)k * DG + n]);
    return;
  }
  idx -= S4;
  if (idx < S5) {
    int k = (int)(idx >> 9), n = (int)(idx & 511);
    WpRP[((size_t)(k >> 3) * NRP + 2048 + n) * 8 + (k & 7)] = f2bf(W_ptr[(size_t)k * 512 + n]);
    return;
  }
  idx -= S5;
  if (idx < S6) {
    int k = (int)idx;
    WpRP[((size_t)(k >> 3) * NRP + 2560) * 8 + (k & 7)] = f2bf(w_mem[k]);
    return;
  }
  idx -= S6;
  if (idx < S7) {
    int k = (int)(idx >> 7), n = (int)(idx & 127);
    WpCI[((size_t)(k >> 3) * 128 + n) * 8 + (k & 7)] = f2bf(W_col_in[(size_t)k * 128 + n]);
  }
}

// Wr2p packed [(2048/8)][128][8]
__global__ __launch_bounds__(256) void r2p_kernel(const float* __restrict__ W_r2,
    const float* __restrict__ prod_embed, const float* __restrict__ b_r2,
    const float* __restrict__ b_lin, ushort_t* __restrict__ Wr2p,
    float* __restrict__ bias2)
{
  int idx = blockIdx.x * 256 + threadIdx.x;
  if (idx >= 2049 * 98) return;
  int k = idx / 98, j = idx - k * 98;
  const float* pe = prod_embed + (size_t)j * DACT;
  if (k < 2048) {
    const float* wr = W_r2 + (size_t)k * DACT;
    float a = 0.f;
    #pragma unroll 8
    for (int d = 0; d < DACT; ++d) a = fmaf(wr[d], pe[d], a);
    Wr2p[((size_t)(k >> 3) * 128 + j) * 8 + (k & 7)] = f2bf(a);
  } else {
    float a = b_lin[j];
    #pragma unroll 8
    for (int d = 0; d < DACT; ++d) a = fmaf(b_r2[d], pe[d], a);
    bias2[j] = a;
  }
}

// appear_all[t][b][c]
__global__ __launch_bounds__(64) void appear_kernel(const int* __restrict__ action_kind,
    const int* __restrict__ tgt_lens, const int* __restrict__ col_ids,
    float* __restrict__ appear_all)
{
  int b = blockIdx.x, c = threadIdx.x;
  float ap = 0.f;
  int tl = tgt_lens[b];
  for (int t = 0; t < NT; ++t) {
    appear_all[((size_t)t * NB + b) * 64 + c] = ap;
    if (t < tl && action_kind[b * NT + t] == 2 && col_ids[b * NT + t] == c) ap = 1.f;
  }
}

// standalone MFMA GEMM, A f32 (used for colin only)
__global__ __launch_bounds__(256) void gemm_bf16(
    const float* __restrict__ A1, int lda1,
    const ushort_t* __restrict__ Bp, ushort_t* __restrict__ Cb, int ldc,
    int N, int K)
{
  __shared__ short As[2][4096];
  __shared__ short Bs[2][4096];
  const int tid = threadIdx.x;
  const int lane = tid & 63, w = tid >> 6;
  const int wr = w >> 1, wc = w & 1;
  const int mBase = blockIdx.y * 64, nBase = blockIdx.x * 64;
  const int nt = K >> 6;
  f32x4 ra0[2], ra1[2];
  short8 rb[2];
  auto issue = [&](int kt) {
    #pragma unroll
    for (int s = 0; s < 2; ++s) {
      int slot = tid + s * 256;
      int kc = slot >> 6, m = slot & 63;
      int k0 = (kt << 6) + kc * 8;
      const float* p = A1 + (size_t)(mBase + m) * lda1 + k0;
      ra0[s] = *(const f32x4*)p;
      ra1[s] = *(const f32x4*)(p + 4);
      rb[s] = *(const short8*)(Bp + ((size_t)(k0 >> 3) * N + nBase + m) * 8);
    }
  };
  auto store = [&](int buf) {
    #pragma unroll
    for (int s = 0; s < 2; ++s) {
      int slot = tid + s * 256;
      short8 av;
      av[0]=(short)f2bf(ra0[s][0]); av[1]=(short)f2bf(ra0[s][1]);
      av[2]=(short)f2bf(ra0[s][2]); av[3]=(short)f2bf(ra0[s][3]);
      av[4]=(short)f2bf(ra1[s][0]); av[5]=(short)f2bf(ra1[s][1]);
      av[6]=(short)f2bf(ra1[s][2]); av[7]=(short)f2bf(ra1[s][3]);
      *(short8*)&As[buf][slot * 8] = av;
      *(short8*)&Bs[buf][slot * 8] = rb[s];
    }
  };
  f32x4 z4 = {0.f,0.f,0.f,0.f};
  f32x4 acc[2][2] = {{z4,z4},{z4,z4}};
  issue(0); store(0);
  __syncthreads();
  int cur = 0;
  for (int kt = 0; kt < nt; ++kt) {
    bool more = (kt + 1 < nt);
    if (more) issue(kt + 1);
    #pragma unroll
    for (int kk = 0; kk < 2; ++kk) {
      int ko = kk * 4 + (lane >> 4);
      short8 af[2], bfr[2];
      #pragma unroll
      for (int f = 0; f < 2; ++f) {
        int row = wr * 32 + f * 16 + (lane & 15);
        af[f] = *(const short8*)&As[cur][(ko * 64 + row) * 8];
        int col = wc * 32 + f * 16 + (lane & 15);
        bfr[f] = *(const short8*)&Bs[cur][(ko * 64 + col) * 8];
      }
      #pragma unroll
      for (int i = 0; i < 2; ++i)
        #pragma unroll
        for (int j = 0; j < 2; ++j)
          acc[i][j] = __builtin_amdgcn_mfma_f32_16x16x32_bf16(af[i], bfr[j], acc[i][j], 0, 0, 0);
    }
    if (more) store(cur ^ 1);
    __syncthreads();
    cur ^= 1;
  }
  #pragma unroll
  for (int i = 0; i < 2; ++i)
    #pragma unroll
    for (int j = 0; j < 2; ++j)
      #pragma unroll
      for (int r = 0; r < 4; ++r) {
        int row = mBase + wr * 32 + i * 16 + (lane >> 4) * 4 + r;
        int col = nBase + wc * 32 + j * 16 + (lane & 15);
        Cb[(size_t)row * ldc + col] = f2bf(acc[i][j][r]);
      }
}

// ---------------- encWq: A-in-LDS, n-loop, B-prefetch; also emits enc_b ----
__global__ __launch_bounds__(256) void gemm_encwq(
    const float* __restrict__ enc, const ushort_t* __restrict__ WqTp,
    ushort_t* __restrict__ encWq, ushort_t* __restrict__ enc_b)
{
  __shared__ short Asm[32768];
  const int tid = threadIdx.x;
  const int lane = tid & 63, w = tid >> 6;
  const int wr = w >> 1, wc = w & 1;
  const int mBase = blockIdx.x * 64;
  #pragma unroll
  for (int it = 0; it < 16; ++it) {
    int o = tid + it * 256;
    int row = o >> 6, c = o & 63;
    short8 v = cvt8(enc + (size_t)(mBase + row) * 512 + c * 8);
    *(short8*)&Asm[row * 512 + ((c ^ (row & 7)) * 8)] = v;
    *(short8*)(enc_b + (size_t)(mBase + row) * 512 + c * 8) = v;
  }
  __syncthreads();
  for (int nt = 0; nt < 8; ++nt) {
    f32x4 z4 = {0.f,0.f,0.f,0.f};
    f32x4 acc[2][2] = {{z4,z4},{z4,z4}};
    short8 bb[2][4];
    auto loadBf = [&](int kt, short8* dst) {
      #pragma unroll
      for (int kk = 0; kk < 2; ++kk)
        #pragma unroll
        for (int f = 0; f < 2; ++f) {
          int ko = kt * 8 + kk * 4 + (lane >> 4);
          int col = nt * 64 + wc * 32 + f * 16 + (lane & 15);
          dst[kk * 2 + f] = *(const short8*)(WqTp + ((size_t)ko * 512 + col) * 8);
        }
    };
    loadBf(0, bb[0]);
    loadBf(1, bb[1]);
    #pragma unroll
    for (int kt = 0; kt < 8; ++kt) {
      short8 cur[4];
      #pragma unroll
      for (int i = 0; i < 4; ++i) cur[i] = bb[kt & 1][i];
      if (kt + 2 < 8) loadBf(kt + 2, bb[kt & 1]);
      #pragma unroll
      for (int kk = 0; kk < 2; ++kk) {
        int ko = kt * 8 + kk * 4 + (lane >> 4);
        short8 af[2];
        #pragma unroll
        for (int f = 0; f < 2; ++f) {
          int row = wr * 32 + f * 16 + (lane & 15);
          af[f] = *(const short8*)&Asm[row * 512 + ((ko ^ (row & 7)) * 8)];
        }
        #pragma unroll
        for (int i = 0; i < 2; ++i)
          #pragma unroll
          for (int j = 0; j < 2; ++j)
            acc[i][j] = __builtin_amdgcn_mfma_f32_16x16x32_bf16(af[i], cur[kk * 2 + j], acc[i][j], 0, 0, 0);
      }
    }
    #pragma unroll
    for (int i = 0; i < 2; ++i)
      #pragma unroll
      for (int j = 0; j < 2; ++j)
        #pragma unroll
        for (int r = 0; r < 4; ++r) {
          int row = mBase + wr * 32 + i * 16 + (lane >> 4) * 4 + r;
          int col = nt * 64 + wc * 32 + j * 16 + (lane & 15);
          encWq[(size_t)row * 512 + col] = f2bf(acc[i][j][r]);
        }
  }
}

// ---------------- core 64x64 MFMA tile engine ------------------------------
template <class FA, class FB, class FE>
__device__ __forceinline__ void gemm_core(char* smem, FA loadA, FB loadB,
    int ktBeg, int ktEnd, FE epi)
{
  short* As = (short*)smem;
  short* Bs = (short*)smem + 8192;
  const int tid = threadIdx.x;
  const int lane = tid & 63, w = tid >> 6;
  const int wr = w >> 1, wc = w & 1;
  f32x4 z4 = {0.f,0.f,0.f,0.f};
  f32x4 acc[2][2] = {{z4,z4},{z4,z4}};
  short8 pa[2], pb[2];
  auto issue = [&](int kt) {
    #pragma unroll
    for (int s = 0; s < 2; ++s) {
      int slot = tid + s * 256;
      int kc = slot >> 6;
      int k = (kt << 6) + (kc << 3);
      pa[s] = loadA(k);
      pb[s] = loadB(slot & 63, k);
    }
  };
  auto store = [&](int buf) {
    #pragma unroll
    for (int s = 0; s < 2; ++s) {
      int slot = tid + s * 256;
      *(short8*)&As[buf * 4096 + slot * 8] = pa[s];
      *(short8*)&Bs[buf * 4096 + slot * 8] = pb[s];
    }
  };
  issue(ktBeg); store(0);
  __syncthreads();
  int cur = 0;
  for (int kt = ktBeg; kt < ktEnd; ++kt) {
    bool more = (kt + 1 < ktEnd);
    if (more) issue(kt + 1);
    #pragma unroll
    for (int kk = 0; kk < 2; ++kk) {
      int ko = kk * 4 + (lane >> 4);
      short8 af[2], bfr[2];
      #pragma unroll
      for (int f = 0; f < 2; ++f) {
        int row = wr * 32 + f * 16 + (lane & 15);
        af[f] = *(const short8*)&As[cur * 4096 + (ko * 64 + row) * 8];
        int col = wc * 32 + f * 16 + (lane & 15);
        bfr[f] = *(const short8*)&Bs[cur * 4096 + (ko * 64 + col) * 8];
      }
      #pragma unroll
      for (int i = 0; i < 2; ++i)
        #pragma unroll
        for (int j = 0; j < 2; ++j)
          acc[i][j] = __builtin_amdgcn_mfma_f32_16x16x32_bf16(af[i], bfr[j], acc[i][j], 0, 0, 0);
    }
    if (more) store(cur ^ 1);
    __syncthreads();
    cur ^= 1;
  }
  #pragma unroll
  for (int i = 0; i < 2; ++i)
    #pragma unroll
    for (int j = 0; j < 2; ++j)
      #pragma unroll
      for (int r = 0; r < 4; ++r) {
        int rl = wr * 32 + i * 16 + (lane >> 4) * 4 + r;
        int cl = wc * 32 + j * 16 + (lane & 15);
        epi(rl, cl, acc[i][j][r]);
      }
}

// ---------------- K1: gates GEMM, split-K x4, f32 out, XCD-swizzled --------
__global__ __launch_bounds__(256) void k1_gates(
    const int* __restrict__ action_kind, const int* __restrict__ tgt_lens,
    const int* __restrict__ prod_ids, const int* __restrict__ col_ids,
    const int* __restrict__ parent_prod, const int* __restrict__ parent_type,
    const int* __restrict__ parent_time,
    const float* __restrict__ prod_embed, const float* __restrict__ type_embed,
    const ushort_t* __restrict__ WpG, const ushort_t* __restrict__ colin_b,
    const ushort_t* __restrict__ att_all, const ushort_t* __restrict__ hist_u,
    float* __restrict__ gates0, float* __restrict__ gates1,
    float* __restrict__ gates2, float* __restrict__ gates3, int t)
{
  __shared__ __align__(16) char smem[32768];
  const int tid = threadIdx.x;
  const int bid = blockIdx.x;
  const int x = bid & 7, j = bid >> 3;
  const int mb = x >> 1;
  const int ks = j >> 4;
  const int nb = ((x & 1) << 4) | (j & 15);
  const int mBase = mb * 64, nBase = nb * 64;
  const int b = mBase + (tid & 63);
  int kp = action_kind[b * NT + t - 1];
  int pp = prod_ids[b * NT + t - 1];
  int cp = col_ids[b * NT + t - 1];
  bool pv = (t - 1) < tgt_lens[b];
  int fp = parent_prod[b * NT + t];
  int ft = parent_type[b * NT + t];
  int ptm = parent_time[b * NT + t];
  const ushort_t* hist_prev = hist_u + (size_t)(t - 1) * NBH;
  const ushort_t* att_prev = att_all + (size_t)(t - 1) * NB * DATT;
  auto loadA = [&](int k) -> short8 {
    short8 z = {0,0,0,0,0,0,0,0};
    if (k < 128) {
      if (!pv) return z;
      if (kp == 2) return *(const short8*)(colin_b + ((size_t)(b * NCOL + cp) * DACT + k));
      int row = (kp == 1) ? 97 : pp;
      return cvt8(prod_embed + (size_t)row * DACT + k);
    } else if (k < 640) {
      return *(const short8*)(att_prev + (size_t)b * DATT + (k - 128));
    } else if (k < 768) {
      return cvt8(prod_embed + (size_t)fp * DACT + (k - 640));
    } else if (k < 832) {
      return cvt8(type_embed + (size_t)ft * DTYP + (k - 768));
    } else if (k < 1344) {
      return *(const short8*)(hist_u + (size_t)ptm * NBH + (size_t)b * DRNN + (k - 832));
    } else {
      return *(const short8*)(hist_prev + (size_t)b * DRNN + (k - 1344));
    }
  };
  auto loadB = [&](int n, int k) -> short8 {
    return *(const short8*)(WpG + ((size_t)(k >> 3) * DG + nBase + n) * 8);
  };
  float* gp = (ks == 0) ? gates0 : (ks == 1) ? gates1 : (ks == 2) ? gates2 : gates3;
  auto epi = [&](int rl, int cl, float v) {
    gp[(size_t)(mBase + rl) * DG + nBase + cl] = v;
  };
  const int kb0 = (ks == 0) ? 0 : (ks == 1) ? 8 : (ks == 2) ? 15 : 22;
  const int kb1 = (ks == 0) ? 8 : (ks == 1) ? 15 : (ks == 2) ? 22 : 29;
  gemm_core(smem, loadA, loadB, kb0, kb1, epi);
}

// ---------------- K23: LSTM (4-way f32 gate sum) + online-softmax attention -
struct SmemK23 { float hq[DRNN]; float ml[4][2]; float cs[4][DENC]; };
__global__ __launch_bounds__(256) void k23_lstm_attn(
    const float* __restrict__ g0, const float* __restrict__ g1,
    const float* __restrict__ g2, const float* __restrict__ g3,
    const float* __restrict__ b_lstm, float* __restrict__ cst,
    ushort_t* __restrict__ hist_t,
    const ushort_t* __restrict__ encWq, const ushort_t* __restrict__ enc_b,
    const int* __restrict__ enc_lens, ushort_t* __restrict__ ctxb)
{
  __shared__ __align__(16) SmemK23 s;
  int b = blockIdx.x, tid = threadIdx.x;
  const float* p0 = g0 + (size_t)b * DG;
  const float* p1 = g1 + (size_t)b * DG;
  const float* p2 = g2 + (size_t)b * DG;
  const float* p3 = g3 + (size_t)b * DG;
  #pragma unroll
  for (int r = 0; r < 2; ++r) {
    int j = tid + r * 256;
    float gi = p0[j] + p1[j] + p2[j] + p3[j] + b_lstm[j];
    float gf = p0[512+j] + p1[512+j] + p2[512+j] + p3[512+j] + b_lstm[512+j];
    float gg = p0[1024+j] + p1[1024+j] + p2[1024+j] + p3[1024+j] + b_lstm[1024+j];
    float go = p0[1536+j] + p1[1536+j] + p2[1536+j] + p3[1536+j] + b_lstm[1536+j];
    size_t ix = (size_t)b * DRNN + j;
    float cn = sigf(gf) * cst[ix] + sigf(gi) * tanhfast(gg);
    float hn = sigf(go) * tanhfast(cn);
    cst[ix] = cn;
    hist_t[ix] = f2bf(hn);
    s.hq[j] = hn;
  }
  __syncthreads();
  int w = tid >> 6, lane = tid & 63;
  int el = enc_lens[b];
  float q[8];
  #pragma unroll
  for (int j = 0; j < 8; ++j) q[j] = s.hq[lane * 8 + j];
  float m = -1e30f, lr = 0.f;
  float cacc[8];
  #pragma unroll
  for (int j = 0; j < 8; ++j) cacc[j] = 0.f;
  const ushort_t* eWb = encWq + (size_t)b * NS * DENC + lane * 8;
  const ushort_t* eb = enc_b + (size_t)b * NS * DENC + lane * 8;
  for (int sI = w; sI < el; sI += 4) {
    short8 xr = *(const short8*)(eWb + (size_t)sI * DENC);
    short8 er = *(const short8*)(eb + (size_t)sI * DENC);
    float d = 0.f;
    #pragma unroll
    for (int j = 0; j < 8; ++j) d = fmaf(bf2f((ushort_t)xr[j]), q[j], d);
    #pragma unroll
    for (int off = 32; off > 0; off >>= 1) d += __shfl_xor(d, off);
    float mn = fmaxf(m, d);
    float rr = __expf(m - mn), p = __expf(d - mn);
    lr = lr * rr + p;
    #pragma unroll
    for (int j = 0; j < 8; ++j) cacc[j] = cacc[j] * rr + p * bf2f((ushort_t)er[j]);
    m = mn;
  }
  if (lane == 0) { s.ml[w][0] = m; s.ml[w][1] = lr; }
  #pragma unroll
  for (int j = 0; j < 8; ++j) s.cs[w][lane * 8 + j] = cacc[j];
  __syncthreads();
  float M = fmaxf(fmaxf(s.ml[0][0], s.ml[1][0]), fmaxf(s.ml[2][0], s.ml[3][0]));
  float f0 = __expf(s.ml[0][0] - M), f1 = __expf(s.ml[1][0] - M);
  float f2 = __expf(s.ml[2][0] - M), f3 = __expf(s.ml[3][0] - M);
  float invL = 1.f / (f0 * s.ml[0][1] + f1 * s.ml[1][1] + f2 * s.ml[2][1] + f3 * s.ml[3][1]);
  #pragma unroll
  for (int rep = 0; rep < 2; ++rep) {
    int d = tid + rep * 256;
    ctxb[(size_t)b * DENC + d] =
        f2bf((f0 * s.cs[0][d] + f1 * s.cs[1][d] + f2 * s.cs[2][d] + f3 * s.cs[3][d]) * invL);
  }
}

// ---------------- K4: att_all[t] = tanh([ctx|h] @ W_att_vec) ---------------
__global__ __launch_bounds__(256) void k4_attvec(const ushort_t* __restrict__ ctxb,
    const ushort_t* __restrict__ hist_t, const ushort_t* __restrict__ WpV,
    ushort_t* __restrict__ att_all, int t)
{
  __shared__ __align__(16) char smem[32768];
  const int tid = threadIdx.x;
  const int mBase = blockIdx.y * 64, nBase = blockIdx.x * 64;
  const int b = mBase + (tid & 63);
  auto loadA = [&](int k) -> short8 {
    if (k < 512) return *(const short8*)(ctxb + (size_t)b * DENC + k);
    return *(const short8*)(hist_t + (size_t)b * DRNN + (k - 512));
  };
  auto loadB = [&](int n, int k) -> short8 {
    return *(const short8*)(WpV + ((size_t)(k >> 3) * 512 + nBase + n) * 8);
  };
  auto epi = [&](int rl, int cl, float v) {
    att_all[((size_t)t * NB + mBase + rl) * DATT + nBase + cl] = f2bf(tanhfast(v));
  };
  gemm_core(smem, loadA, loadB, 0, 16, epi);
}

// ---------------- tail: r1|ptr|gate GEMM, 64x128 tile, XCD-swizzled --------
__global__ __launch_bounds__(256) void kbig_r1ptr(const ushort_t* __restrict__ att_all,
    const ushort_t* __restrict__ WpRP, const float* __restrict__ b_r1,
    ushort_t* __restrict__ r1c, ushort_t* __restrict__ ptrq_all,
    float* __restrict__ gate_all, int rowBase)
{
  __shared__ short As[2][4096];
  __shared__ short Bs[2][8192];
  const int tid = threadIdx.x;
  const int lane = tid & 63, w = tid >> 6;
  const int wr = w >> 1, wc = w & 1;
  const int bid = blockIdx.x;
  const int x = bid & 7, j = bid >> 3;
  const int mb = x * 15 + j / 21;
  const int ng = j % 21;
  const int mBase = mb * 64, nBase = ng * 128;
  short8 pa[2], pb[4];
  auto issue = [&](int kt) {
    #pragma unroll
    for (int s = 0; s < 2; ++s) {
      int slot = tid + s * 256;
      int kc = slot >> 6, m = slot & 63;
      int k = (kt << 6) + (kc << 3);
      pa[s] = *(const short8*)(att_all + ((size_t)rowBase + mBase + m) * DATT + k);
    }
    #pragma unroll
    for (int s = 0; s < 4; ++s) {
      int slot = tid + s * 256;
      int kc = slot >> 7, n = slot & 127;
      int k = (kt << 6) + (kc << 3);
      pb[s] = *(const short8*)(WpRP + ((size_t)(k >> 3) * NRP + nBase + n) * 8);
    }
  };
  auto store = [&](int buf) {
    #pragma unroll
    for (int s = 0; s < 2; ++s) {
      int slot = tid + s * 256;
      *(short8*)&As[buf][slot * 8] = pa[s];
    }
    #pragma unroll
    for (int s = 0; s < 4; ++s) {
      int slot = tid + s * 256;
      *(short8*)&Bs[buf][slot * 8] = pb[s];
    }
  };
  f32x4 z4 = {0.f,0.f,0.f,0.f};
  f32x4 acc[2][4] = {{z4,z4,z4,z4},{z4,z4,z4,z4}};
  issue(0); store(0);
  __syncthreads();
  int cur = 0;
  for (int kt = 0; kt < 8; ++kt) {
    bool more = (kt + 1 < 8);
    if (more) issue(kt + 1);
    #pragma unroll
    for (int kk = 0; kk < 2; ++kk) {
      int ko = kk * 4 + (lane >> 4);
      short8 af[2], bfr[4];
      #pragma unroll
      for (int f = 0; f < 2; ++f) {
        int row = wr * 32 + f * 16 + (lane & 15);
        af[f] = *(const short8*)&As[cur][(ko * 64 + row) * 8];
      }
      #pragma unroll
      for (int f = 0; f < 4; ++f) {
        int col = wc * 64 + f * 16 + (lane & 15);
        bfr[f] = *(const short8*)&Bs[cur][(ko * 128 + col) * 8];
      }
      #pragma unroll
      for (int i = 0; i < 2; ++i)
        #pragma unroll
        for (int jf = 0; jf < 4; ++jf)
          acc[i][jf] = __builtin_amdgcn_mfma_f32_16x16x32_bf16(af[i], bfr[jf], acc[i][jf], 0, 0, 0);
    }
    if (more) store(cur ^ 1);
    __syncthreads();
    cur ^= 1;
  }
  #pragma unroll
  for (int i = 0; i < 2; ++i)
    #pragma unroll
    for (int jf = 0; jf < 4; ++jf)
      #pragma unroll
      for (int r = 0; r < 4; ++r) {
        int rl = wr * 32 + i * 16 + (lane >> 4) * 4 + r;
        int col = nBase + wc * 64 + jf * 16 + (lane & 15);
        size_t gr = (size_t)rowBase + mBase + rl;
        float v = acc[i][jf][r];
        if (col < 2048)      r1c[(size_t)(mBase + rl) * DG + col] = f2bf(tanhfast(v + b_r1[col]));
        else if (col < 2560) ptrq_all[((size_t)(gr & 255) * NT + (gr >> 8)) * RPW + (col - 2048)] = f2bf(v);
        else if (col == 2560) gate_all[gr] = v;
      }
}

// ---------------- tail: logits GEMM (XCD-swizzled 1D grid, 240 blocks) -----
__global__ __launch_bounds__(256) void klogits(const ushort_t* __restrict__ r1c,
    const ushort_t* __restrict__ Wr2p, float* __restrict__ logits_all, int rowBase)
{
  __shared__ __align__(16) char smem[32768];
  const int tid = threadIdx.x;
  const int bid = blockIdx.x;
  const int x = bid & 7, j = bid >> 3;
  const int mb = x * 15 + (j >> 1);
  const int nb = j & 1;
  const int mBase = mb * 64, nBase = nb * 64;
  auto loadA = [&](int k) -> short8 {
    return *(const short8*)(r1c + (size_t)(mBase + (tid & 63)) * DG + k);
  };
  auto loadB = [&](int n, int k) -> short8 {
    return *(const short8*)(Wr2p + ((size_t)(k >> 3) * 128 + nBase + n) * 8);
  };
  auto epi = [&](int rl, int cl, float v) {
    logits_all[((size_t)rowBase + mBase + rl) * 128 + nBase + cl] = v;
  };
  gemm_core(smem, loadA, loadB, 0, 32, epi);
}

// ---------------- tail: w_c ------------------------------------------------
__global__ __launch_bounds__(256) void kwc(const ushort_t* __restrict__ ptrq_all,
    const ushort_t* __restrict__ colenc_b, float* __restrict__ w_c_all)
{
  __shared__ __align__(16) char smem[32768];
  const int tid = threadIdx.x;
  const int b = blockIdx.x;
  const int tt = tid & 63;
  auto loadA = [&](int k) -> short8 {
    short8 z = {0,0,0,0,0,0,0,0};
    if (tt >= NT) return z;
    return *(const short8*)(ptrq_all + ((size_t)b * NT + tt) * RPW + k);
  };
  auto loadB = [&](int n, int k) -> short8 {
    return *(const short8*)(colenc_b + ((size_t)b * NCOL + n) * 512 + k);
  };
  auto epi = [&](int rl, int cl, float v) {
    if (rl < NT) w_c_all[((size_t)rl * NB + b) * 64 + cl] = v;
  };
  gemm_core(smem, loadA, loadB, 0, 8, epi);
}

// ---------------- tail: per-(t,b) softmaxes + loss -------------------------
__global__ __launch_bounds__(64) void kfinal(
    const float* __restrict__ logits_all, const float* __restrict__ bias2,
    const float* __restrict__ w_c_all, const float* __restrict__ gate_all,
    const float* __restrict__ appear_all, const int* __restrict__ col_lens,
    const int* __restrict__ tgt_lens, const int* __restrict__ action_kind,
    const int* __restrict__ prod_ids, const int* __restrict__ col_ids,
    float* __restrict__ loss_tb)
{
  int row = blockIdx.x;
  int t = row >> 8, b = row & 255;
  int c = threadIdx.x;
  float l0 = logits_all[(size_t)row * 128 + c] + bias2[c];
  float l1 = (c + 64 < 98) ? logits_all[(size_t)row * 128 + 64 + c] + bias2[64 + c] : -1e30f;
  float m = fmaxf(l0, l1);
  #pragma unroll
  for (int off = 32; off > 0; off >>= 1) m = fmaxf(m, __shfl_down(m, off));
  m = __shfl(m, 0);
  float sv = __expf(l0 - m) + ((c + 64 < 98) ? __expf(l1 - m) : 0.f);
  #pragma unroll
  for (int off = 32; off > 0; off >>= 1) sv += __shfl_down(sv, off);
  sv = __shfl(sv, 0);
  float lseR = m + __logf(sv);
  int clen = col_lens[b];
  float gate = sigf(gate_all[row]);
  float ap = appear_all[(size_t)row * 64 + c];
  float wc = w_c_all[(size_t)row * 64 + c];
  float wv = wc * (ap * gate + (1.f - ap) * (1.f - gate));
  wv = (c < clen) ? wv : NEGV;
  float m2 = wv;
  #pragma unroll
  for (int off = 32; off > 0; off >>= 1) m2 = fmaxf(m2, __shfl_down(m2, off));
  m2 = __shfl(m2, 0);
  float s2 = __expf(wv - m2);
  #pragma unroll
  for (int off = 32; off > 0; off >>= 1) s2 += __shfl_down(s2, off);
  s2 = __shfl(s2, 0);
  float lse2 = m2 + __logf(s2);
  float csum = (c < clen) ? (wv - lse2) : 0.f;
  #pragma unroll
  for (int off = 32; off > 0; off >>= 1) csum += __shfl_down(csum, off);
  int kind = action_kind[b * NT + t];
  int cid = col_ids[b * NT + t];
  float wcid = __shfl(wv, cid);
  if (c == 0) {
    int pid = prod_ids[b * NT + t];
    bool valid = t < tgt_lens[b];
    int gj = (kind == 1) ? 97 : pid;
    float lgj = logits_all[(size_t)row * 128 + gj] + bias2[gj];
    float lp_rule = lgj - lseR;
    float lp_col = 0.8f * (wcid - lse2) + 0.2f * csum / (float)clen;
    float lp = (kind == 2) ? lp_col : lp_rule;
    loss_tb[row] = valid ? lp : 0.f;
  }
}

// -------------------------------------------------------------------------
__global__ __launch_bounds__(256) void loss_reduce(const float* __restrict__ loss_tb,
                                                   float* __restrict__ out) {
  int tid = threadIdx.x;
  float v = 0.f;
  for (int k = 0; k < NT; ++k) v += loss_tb[(size_t)k * NB + tid];
  #pragma unroll
  for (int off = 32; off > 0; off >>= 1) v += __shfl_down(v, off);
  __shared__ float part[4];
  if ((tid & 63) == 0) part[tid >> 6] = v;
  __syncthreads();
  if (tid == 0) out[0] = -(part[0] + part[1] + part[2] + part[3]) * (1.0f / NB);
}

// -------------------------------------------------------------------------
extern "C" void kernel_launch(void* const* d_in, const int* in_sizes, int n_in,
                              void* d_out, int out_size, void* d_ws, size_t ws_size,
                              hipStream_t stream) {
  const float* enc         = (const float*)d_in[0];
  const float* col_enc     = (const float*)d_in[1];
  const int*   enc_lens    = (const int*)d_in[2];
  const int*   col_lens    = (const int*)d_in[3];
  const int*   action_kind = (const int*)d_in[4];
  const int*   tgt_lens    = (const int*)d_in[5];
  const int*   prod_ids    = (const int*)d_in[6];
  const int*   col_ids     = (const int*)d_in[7];
  const int*   parent_prod = (const int*)d_in[8];
  const int*   parent_type = (const int*)d_in[9];
  const int*   parent_time = (const int*)d_in[10];
  const float* prod_embed  = (const float*)d_in[11];
  const float* type_embed  = (const float*)d_in[12];
  const float* b_lin       = (const float*)d_in[13];
  const float* W_ih        = (const float*)d_in[14];
  const float* W_hh        = (const float*)d_in[15];
  const float* b_lstm      = (const float*)d_in[16];
  const float* W_att_q     = (const float*)d_in[17];
  const float* W_att_vec   = (const float*)d_in[18];
  const float* W_r1        = (const float*)d_in[19];
  const float* b_r1        = (const float*)d_in[20];
  const float* W_r2        = (const float*)d_in[21];
  const float* b_r2        = (const float*)d_in[22];
  const float* W_col_in    = (const float*)d_in[23];
  const float* W_ptr       = (const float*)d_in[24];
  const float* w_mem       = (const float*)d_in[25];

  float* base = (float*)d_ws;
  size_t o = 0;
  float* cst    = base + o; o += 131072;
  float* gates0 = base + o; o += 524288;
  float* gates1 = base + o; o += 524288;
  float* gates2 = base + o; o += 524288;
  float* gates3 = base + o; o += 524288;
  int zeroN = (int)o;                                   // 2,228,224
  ushort_t* hist_u = (ushort_t*)(base + o); o += 3932160;   // loop; tail alias: logits_all
  float* logits_all = (float*)hist_u;
  ushort_t* colin_b = (ushort_t*)(base + o); o += 1048576;
  float* encWq_f    = base + o; o += 8388608;               // loop: encWq; tail alias: r1c
  ushort_t* encWq   = (ushort_t*)encWq_f;
  ushort_t* r1c     = (ushort_t*)encWq_f;
  float* encb_f     = base + o; o += 4194304;               // loop: enc_b; tail alias: colenc_b
  ushort_t* enc_b   = (ushort_t*)encb_f;
  ushort_t* colenc_b = (ushort_t*)encb_f;
  ushort_t* att_all  = (ushort_t*)(base + o); o += 3932160; // [15360][512] bf16
  ushort_t* ptrq_all = (ushort_t*)(base + o); o += 3932160; // [256][60][512] bf16; loop alias: ctxb
  ushort_t* ctxb     = ptrq_all;
  float* gate_all    = base + o; o += 15360;
  float* w_c_all     = base + o; o += 983040;
  float* appear_all  = base + o; o += 983040;
  float* loss_tb     = base + o; o += 15360;
  ushort_t* WpG   = (ushort_t*)(base + o); o += 1900544;
  ushort_t* WqTp  = (ushort_t*)(base + o); o += 131072;
  ushort_t* WpV   = (ushort_t*)(base + o); o += 262144;
  ushort_t* WpRP  = (ushort_t*)(base + o); o += 688128;     // [(512/8)][2688][8]
  ushort_t* WpCI  = (ushort_t*)(base + o); o += 32768;
  ushort_t* Wr2p  = (ushort_t*)(base + o); o += 131072;
  float* bias2    = base + o; o += 128;
  (void)ws_size; (void)in_sizes; (void)n_in; (void)out_size;

  zero_kernel<<<(zeroN + 255) / 256, 256, 0, stream>>>(base, zeroN);

  pack_all<<<(PACK_TOT + 255) / 256, 256, 0, stream>>>(
      W_ih, W_hh, W_att_q, W_att_vec, W_r1, W_ptr, w_mem, W_col_in,
      WpG, WqTp, WpV, WpRP, WpCI);
  r2p_kernel<<<(2049 * 98 + 255) / 256, 256, 0, stream>>>(W_r2, prod_embed, b_r2, b_lin, Wr2p, bias2);
  appear_kernel<<<NB, 64, 0, stream>>>(action_kind, tgt_lens, col_ids, appear_all);

  gemm_bf16<<<dim3(2, 256), 256, 0, stream>>>(col_enc, 512, WpCI, colin_b, 128, 128, 512);
  gemm_encwq<<<512, 256, 0, stream>>>(enc, WqTp, encWq, enc_b);

  // ---- recurrent loop: 3 nodes/step ----
  for (int t = 0; t < NT; ++t) {
    ushort_t* hist_t = hist_u + (size_t)t * NBH;
    if (t > 0)
      k1_gates<<<512, 256, 0, stream>>>(
          action_kind, tgt_lens, prod_ids, col_ids, parent_prod, parent_type,
          parent_time, prod_embed, type_embed, WpG, colin_b, att_all, hist_u,
          gates0, gates1, gates2, gates3, t);
    k23_lstm_attn<<<NB, 256, 0, stream>>>(gates0, gates1, gates2, gates3,
        b_lstm, cst, hist_t, encWq, enc_b, enc_lens, ctxb);
    k4_attvec<<<dim3(8, 4), 256, 0, stream>>>(ctxb, hist_t, WpV, att_all, t);
  }

  // ---- batched tail (2 chunks of 7680 rows) ----
  cvt_bf16_kernel<<<(1048576 + 255) / 256, 256, 0, stream>>>(col_enc, colenc_b, 1048576);
  for (int ch = 0; ch < 2; ++ch) {
    int rowBase = ch * 7680;
    kbig_r1ptr<<<2520, 256, 0, stream>>>(att_all, WpRP, b_r1, r1c,
                                         ptrq_all, gate_all, rowBase);
    klogits<<<240, 256, 0, stream>>>(r1c, Wr2p, logits_all, rowBase);
  }
  kwc<<<NB, 256, 0, stream>>>(ptrq_all, colenc_b, w_c_all);
  kfinal<<<NROW, 64, 0, stream>>>(logits_all, bias2, w_c_all, gate_all,
      appear_all, col_lens, tgt_lens, action_kind, prod_ids, col_ids, loss_tb);
  loss_reduce<<<1, 256, 0, stream>>>(loss_tb, (float*)d_out);
}